// Round 1
// 474.505 us; speedup vs baseline: 1.0072x; 1.0072x over previous
//
#include <hip/hip_runtime.h>

// ---------------------------------------------------------------------------
// GAT (2-layer) on MI355X. fp32 tensors, adj int32. N = 8192, D = 64.
//   k_prep*  : Wh = x@W^T+b -> WhT (f16 [feature][node]) + f16 exp tables.
//   k_agg_l0 : FUSED adj->bitmask + masked-softmax aggregation. Each wave
//              ballots its own 32 mask rows from raw adj (256 KB/block, adj
//              streamed exactly once across the grid, overlapped with MFMA),
//              stores them to LDS AND to global bits for layer 1.
//   k_agg_l1 : same aggregation, masks read from the 8 MB bitmask.
//              w = exp(lrelu(s+d)) = max(e^s e^d, e^.2s e^.2d): pk_mul x2 +
//              pk_max + bit-AND mask (no transcendental/cmp/cvt in loop).
//              Blocks: 128 rows x 512 k (grid 64x16, zero tail). WhT slice
//              staged in MFMA-FRAGMENT ORDER [k-octet][feature] with +g mod-64
//              rotation: B-fragment ds_reads are contiguous/aligned/conflict-
//              free. Register-prefetched staging, 4 chunks of 128 k.
//              Epilogue: direct stores (32x32 C/D rows are 128 B runs).
//   k_out    : out = relu(sum(numP)/sum(denP)) @ out_w^T + out_b (fp32).
// Workspace ~43 MB. No atomics, no memsets.
// ---------------------------------------------------------------------------

typedef _Float16 f16x8 __attribute__((ext_vector_type(8)));
typedef _Float16 f16x2 __attribute__((ext_vector_type(2)));
typedef float    f32x16 __attribute__((ext_vector_type(16)));

union Frag16 {
    f16x8        v;
    unsigned int u[4];
};
union HV2 {
    f16x2        v;
    _Float16     h[2];
    unsigned int u;
};

// ------------------------------- prep --------------------------------------
__device__ __forceinline__ void prep_tail(
    float (*xs)[65], float (*Wt)[65], float (*sred)[64], float (*dred)[64],
    const float* __restrict__ W, const float* __restrict__ bias,
    const float* __restrict__ avec,
    _Float16* __restrict__ WhT,
    unsigned int* __restrict__ E12,
    _Float16* __restrict__ F1h, _Float16* __restrict__ F2h,
    int tid, int r0)
{
    for (int e = tid; e < 4096; e += 256) {
        int o = e >> 6, c = e & 63;
        Wt[c][o] = W[e];                       // W[o][c] -> transposed LDS
    }
    __syncthreads();

    int r = tid & 63, chunk = tid >> 6, c0 = chunk * 16;
    float acc[16];
#pragma unroll
    for (int o = 0; o < 16; o++) acc[o] = bias[c0 + o];
    for (int c = 0; c < 64; c++) {
        float xv = xs[r][c];
#pragma unroll
        for (int o = 0; o < 16; o++) acc[o] += xv * Wt[c][c0 + o];
    }

    float sp = 0.f, dp = 0.f;
#pragma unroll
    for (int o = 0; o < 16; o++) {
        sp += acc[o] * avec[c0 + o];           // a[:64]
        dp += acc[o] * avec[64 + c0 + o];      // a[64:]
    }
    sred[chunk][r] = sp;
    dred[chunk][r] = dp;

#pragma unroll
    for (int o = 0; o < 16; o++)
        WhT[(size_t)(c0 + o) * 8192 + r0 + r] = (_Float16)acc[o];

    __syncthreads();
    if (tid < 64) {
        int g = r0 + tid;
        float s = sred[0][tid] + sred[1][tid] + sred[2][tid] + sred[3][tid];
        float d = dred[0][tid] + dred[1][tid] + dred[2][tid] + dred[3][tid];
        HV2 e;
        e.h[0] = (_Float16)__expf(s);          // e^s       (lo)
        e.h[1] = (_Float16)__expf(0.2f * s);   // e^{0.2s}  (hi)
        E12[g] = e.u;
        F1h[g] = (_Float16)__expf(d);
        F2h[g] = (_Float16)__expf(0.2f * d);
    }
}

__global__ __launch_bounds__(256) void k_prep0(
    const float* __restrict__ ue, const float* __restrict__ ie,
    const float* __restrict__ W, const float* __restrict__ bias,
    const float* __restrict__ avec,
    _Float16* __restrict__ WhT, unsigned int* __restrict__ E12,
    _Float16* __restrict__ F1h, _Float16* __restrict__ F2h)
{
    __shared__ float xs[64][65];
    __shared__ float Wt[64][65];
    __shared__ float sred[4][64];
    __shared__ float dred[4][64];
    int tid = threadIdx.x, r0 = blockIdx.x * 64;

    for (int e = tid; e < 4096; e += 256) {
        int r = e >> 6, c = e & 63;
        int row = r0 + r;
        xs[r][c] = (row < 4096) ? ue[row * 64 + c] : ie[(row - 4096) * 64 + c];
    }
    prep_tail(xs, Wt, sred, dred, W, bias, avec, WhT, E12, F1h, F2h, tid, r0);
}

// numP layout: [ks][rowblk128][128*64] tiles; denP: [ks][8192].
template <int NS>
__global__ __launch_bounds__(256) void k_prep1(
    const float* __restrict__ numP, const float* __restrict__ denP,
    const float* __restrict__ W, const float* __restrict__ bias,
    const float* __restrict__ avec,
    _Float16* __restrict__ WhT, unsigned int* __restrict__ E12,
    _Float16* __restrict__ F1h, _Float16* __restrict__ F2h)
{
    __shared__ float xs[64][65];
    __shared__ float Wt[64][65];
    __shared__ float sred[4][64];
    __shared__ float dred[4][64];
    __shared__ float dtot[64];
    int tid = threadIdx.x, r0 = blockIdx.x * 64;
    int rb128 = blockIdx.x >> 1, half = blockIdx.x & 1;

    if (tid < 64) {
        float s = 0.f;
#pragma unroll
        for (int p = 0; p < NS; p++) s += denP[p * 8192 + r0 + tid];
        dtot[tid] = fmaxf(s, 1e-20f);
    }
    __syncthreads();
    for (int e = tid; e < 4096; e += 256) {
        int r = e >> 6;
        float s = 0.f;
#pragma unroll
        for (int p = 0; p < NS; p++)
            s += numP[(size_t)(p * 64 + rb128) * 8192 + half * 4096 + e];
        float v = s / dtot[r];
        xs[r][e & 63] = v > 0.f ? v : 0.f;
    }
    prep_tail(xs, Wt, sred, dred, W, bias, avec, WhT, E12, F1h, F2h, tid, r0);
}

// --------------------------- aggregation (core) ----------------------------
// grid (64, 16): 128-row block x 512-k split, 4 chunks of 128 k.
// MFMA 32x32x16 f16. A[m=lane&31][k=(lane>>5)*8+j];
// C/D: col=lane&31, row=(reg&3)+8*(reg>>2)+4*(lane>>5).
// WhBf fragment-order: slot(g,f) = g*64 + ((f+g)&63), g = k-octet (0..15/chunk).
struct AggSmem {
    uint4        WhBf[1024];                   // 16 KB: [g][f-rot] 8-half slots
    unsigned int mkAll[128][20];               // 10240 B (16 words used)
    unsigned int f1All[256];                   // 512 halves
    unsigned int f2All[256];                   // 512 halves
};                                             // 28672 B

template <bool BUILD>
__device__ __forceinline__ void agg_body(
    const int* __restrict__ adj,               // BUILD only
    unsigned long long* __restrict__ bitsOut,  // BUILD only
    const unsigned int* __restrict__ bits,     // !BUILD only
    const _Float16* __restrict__ WhT, const unsigned int* __restrict__ E12,
    const _Float16* __restrict__ F1h, const _Float16* __restrict__ F2h,
    float* __restrict__ numP, float* __restrict__ denP)
{
    constexpr int CK = 128, NCH = 4;           // 512 k per block
    __shared__ AggSmem sm;

    int tid  = threadIdx.x;
    int wave = tid >> 6, lane = tid & 63;
    int l32 = lane & 31, khalf = lane >> 5;
    int rowblk = blockIdx.x, ks = blockIdx.y;
    int k0 = ks * (CK * NCH);

    // ---- WhBf staging loads issued first (land during mask build) ----
    uint4 P[4];
#pragma unroll
    for (int i = 0; i < 4; i++) {
        int ff = (tid >> 3) + (i & 1) * 32, gg = (tid & 7) + (i >> 1) * 8;
        P[i] = *reinterpret_cast<const uint4*>(WhT + (size_t)ff * 8192 + k0 + gg * 8);
    }

    // ---- exp tables for the 512-k range ----
    if (tid < 64) {
        uint4 v = *reinterpret_cast<const uint4*>(F1h + k0 + tid * 8);
        *reinterpret_cast<uint4*>(&sm.f1All[tid * 4]) = v;
    } else if (tid < 128) {
        int t2 = tid - 64;
        uint4 v = *reinterpret_cast<const uint4*>(F2h + k0 + t2 * 8);
        *reinterpret_cast<uint4*>(&sm.f2All[t2 * 4]) = v;
    }

    // ---- masks: 128 rows x 16 words (each wave owns its 32 rows) ----
    if constexpr (BUILD) {
        // ballot raw adj -> LDS masks + global bits (for layer 1).
        int rbase = rowblk * 128;
        for (int t = 0; t < 32; t += 2) {
            int ra = wave * 32 + t;
            const int* apa = adj + (size_t)(rbase + ra) * 8192 + k0;
            const int* apb = apa + 8192;
            int a0[8], a1[8];
#pragma unroll
            for (int j = 0; j < 8; j++) a0[j] = apa[j * 64 + lane];
#pragma unroll
            for (int j = 0; j < 8; j++) a1[j] = apb[j * 64 + lane];
            unsigned long long m0[8], m1[8];
#pragma unroll
            for (int j = 0; j < 8; j++) m0[j] = __ballot(a0[j] != 0);
#pragma unroll
            for (int j = 0; j < 8; j++) m1[j] = __ballot(a1[j] != 0);
            if (lane < 4) {
                ulonglong2 v0{m0[2 * lane], m0[2 * lane + 1]};
                ulonglong2 v1{m1[2 * lane], m1[2 * lane + 1]};
                *reinterpret_cast<ulonglong2*>(&sm.mkAll[ra][lane * 4])     = v0;
                *reinterpret_cast<ulonglong2*>(&sm.mkAll[ra + 1][lane * 4]) = v1;
                reinterpret_cast<ulonglong2*>(
                    bitsOut + (((size_t)(rbase + ra)) << 7) + ks * 8)[lane] = v0;
                reinterpret_cast<ulonglong2*>(
                    bitsOut + (((size_t)(rbase + ra + 1)) << 7) + ks * 8)[lane] = v1;
            }
        }
    } else {
#pragma unroll
        for (int j = 0; j < 2; j++) {
            int s = tid + 256 * j;
            int row_l = s >> 2, q = s & 3;
            uint4 v = *reinterpret_cast<const uint4*>(
                bits + (size_t)(rowblk * 128 + row_l) * 256 + ks * 16 + q * 4);
            *reinterpret_cast<uint4*>(&sm.mkAll[row_l][q * 4]) = v;
        }
    }

    // ---- WhBf staging stores: thread t covers (f=t>>3 [+32], g=t&7 [+8]) ----
#pragma unroll
    for (int i = 0; i < 4; i++) {
        int ff = (tid >> 3) + (i & 1) * 32, gg = (tid & 7) + (i >> 1) * 8;
        sm.WhBf[gg * 64 + ((ff + gg) & 63)] = P[i];
    }
    __syncthreads();

    int row = rowblk * 128 + wave * 32 + l32;
    int lrow = wave * 32 + l32;
    unsigned int e12 = E12[row];
    HV2 e1p, e2p;
    e1p.u = (e12 & 0xFFFFu);  e1p.u |= e1p.u << 16;   // {e^s, e^s}
    e2p.u = (e12 >> 16);      e2p.u |= e2p.u << 16;   // {e^.2s, e^.2s}

    f32x16 acc0 = {}, acc1 = {}, accd = {};

    Frag16 ones;
    ones.u[0] = ones.u[1] = ones.u[2] = ones.u[3] = 0x3C003C00u;  // f16 1.0

    for (int c = 0; c < NCH; c++) {
        if (c + 1 < NCH) {                     // prefetch next chunk's WhT
            int kc = k0 + (c + 1) * CK;
#pragma unroll
            for (int i = 0; i < 4; i++) {
                int ff = (tid >> 3) + (i & 1) * 32, gg = (tid & 7) + (i >> 1) * 8;
                P[i] = *reinterpret_cast<const uint4*>(
                    WhT + (size_t)ff * 8192 + kc + gg * 8);
            }
        }

#pragma unroll
        for (int kb = 0; kb < CK; kb += 16) {
            int wi = kb + khalf * 8;           // lane's k-offset in chunk
            unsigned int word = sm.mkAll[lrow][c * 4 + (wi >> 5)];
            unsigned int w8 = word >> (wi & 31);

            int fidx = (c * CK + wi) >> 1;     // uint index into f tables
            uint4 f1v = *reinterpret_cast<const uint4*>(&sm.f1All[fidx]);
            uint4 f2v = *reinterpret_cast<const uint4*>(&sm.f2All[fidx]);
            unsigned int f1a[4] = {f1v.x, f1v.y, f1v.z, f1v.w};
            unsigned int f2a[4] = {f2v.x, f2v.y, f2v.z, f2v.w};

            Frag16 A;
#pragma unroll
            for (int p = 0; p < 4; p++) {
                HV2 fa, fb, wa;
                fa.u = f1a[p];
                fb.u = f2a[p];
                // exp(lrelu(s+d)) = max(e^s e^d, e^.2s e^.2d)
                wa.v = __builtin_elementwise_max(e1p.v * fa.v, e2p.v * fb.v);
                int s0 = ((int)(w8 << (31 - 2 * p))) >> 31;   // sext bit 2p
                int s1 = ((int)(w8 << (30 - 2 * p))) >> 31;   // sext bit 2p+1
                unsigned int pm = ((unsigned)s0 & 0xFFFFu) | ((unsigned)s1 << 16);
                A.u[p] = wa.u & pm;
            }

            int g0 = (kb >> 3) + khalf;        // lane's k-octet index
            Frag16 B0, B1;
            B0.v = *reinterpret_cast<const f16x8*>(
                &sm.WhBf[g0 * 64 + ((l32 + g0) & 63)]);
            B1.v = *reinterpret_cast<const f16x8*>(
                &sm.WhBf[g0 * 64 + ((32 + l32 + g0) & 63)]);
            acc0 = __builtin_amdgcn_mfma_f32_32x32x16_f16(A.v, B0.v, acc0, 0, 0, 0);
            acc1 = __builtin_amdgcn_mfma_f32_32x32x16_f16(A.v, B1.v, acc1, 0, 0, 0);
            accd = __builtin_amdgcn_mfma_f32_32x32x16_f16(A.v, ones.v, accd, 0, 0, 0);
        }

        if (c + 1 < NCH) {
            __syncthreads();                   // done reading chunk c
#pragma unroll
            for (int i = 0; i < 4; i++) {
                int ff = (tid >> 3) + (i & 1) * 32, gg = (tid & 7) + (i >> 1) * 8;
                sm.WhBf[gg * 64 + ((ff + gg) & 63)] = P[i];
            }
            __syncthreads();                   // chunk c+1 visible
        }
    }

    // ---- epilogue: direct coalesced stores (each inst = 2 full sectors) ----
    float* tile = numP + (size_t)(ks * 64 + rowblk) * 8192;
#pragma unroll
    for (int r = 0; r < 16; r++) {
        int rl = wave * 32 + (r & 3) + 8 * (r >> 2) + 4 * khalf;
        tile[rl * 64 + l32]      = acc0[r];
        tile[rl * 64 + 32 + l32] = acc1[r];
        if (l32 == 0)
            denP[ks * 8192 + rowblk * 128 + rl] = accd[r];
    }
}

__global__ __launch_bounds__(256) void k_agg_l0(
    const int* __restrict__ adj, unsigned long long* __restrict__ bitsOut,
    const _Float16* __restrict__ WhT, const unsigned int* __restrict__ E12,
    const _Float16* __restrict__ F1h, const _Float16* __restrict__ F2h,
    float* __restrict__ numP, float* __restrict__ denP)
{
    agg_body<true>(adj, bitsOut, nullptr, WhT, E12, F1h, F2h, numP, denP);
}

__global__ __launch_bounds__(256) void k_agg_l1(
    const unsigned int* __restrict__ bits,
    const _Float16* __restrict__ WhT, const unsigned int* __restrict__ E12,
    const _Float16* __restrict__ F1h, const _Float16* __restrict__ F2h,
    float* __restrict__ numP, float* __restrict__ denP)
{
    agg_body<false>(nullptr, nullptr, bits, WhT, E12, F1h, F2h, numP, denP);
}

// ----------------------------- output GEMM ---------------------------------
template <int NS>
__global__ __launch_bounds__(256) void k_out(
    const float* __restrict__ numP, const float* __restrict__ denP,
    const float* __restrict__ W, const float* __restrict__ bias,
    float* __restrict__ out)
{
    __shared__ float xs[64][65];
    __shared__ float Wt[64][65];
    __shared__ float dtot[64];
    int tid = threadIdx.x, r0 = blockIdx.x * 64;
    int rb128 = blockIdx.x >> 1, half = blockIdx.x & 1;

    if (tid < 64) {
        float s = 0.f;
#pragma unroll
        for (int p = 0; p < NS; p++) s += denP[p * 8192 + r0 + tid];
        dtot[tid] = fmaxf(s, 1e-20f);
    }
    __syncthreads();
    for (int e = tid; e < 4096; e += 256) {
        int r = e >> 6;
        float s = 0.f;
#pragma unroll
        for (int p = 0; p < NS; p++)
            s += numP[(size_t)(p * 64 + rb128) * 8192 + half * 4096 + e];
        float v = s / dtot[r];
        xs[r][e & 63] = v > 0.f ? v : 0.f;
    }
    for (int e = tid; e < 4096; e += 256) {
        int o = e >> 6, c = e & 63;
        Wt[c][o] = W[e];
    }
    __syncthreads();

    int r = tid & 63, chunk = tid >> 6, c0 = chunk * 16;
    float acc[16];
#pragma unroll
    for (int o = 0; o < 16; o++) acc[o] = bias[c0 + o];
    for (int c = 0; c < 64; c++) {
        float xv = xs[r][c];
#pragma unroll
        for (int o = 0; o < 16; o++) acc[o] += xv * Wt[c][c0 + o];
    }
#pragma unroll
    for (int o = 0; o < 16; o++)
        out[(r0 + r) * 64 + c0 + o] = acc[o];
}

// ------------------------------- launch ------------------------------------
extern "C" void kernel_launch(void* const* d_in, const int* in_sizes, int n_in,
                              void* d_out, int out_size, void* d_ws, size_t ws_size,
                              hipStream_t stream)
{
    const int*   adj = (const int*)d_in[0];
    const float* ue  = (const float*)d_in[1];
    const float* ie  = (const float*)d_in[2];
    const float* W0w = (const float*)d_in[3];
    const float* W0b = (const float*)d_in[4];
    const float* a0  = (const float*)d_in[5];
    const float* W1w = (const float*)d_in[6];
    const float* W1b = (const float*)d_in[7];
    const float* a1  = (const float*)d_in[8];
    const float* Ow  = (const float*)d_in[9];
    const float* Ob  = (const float*)d_in[10];

    constexpr int NS = 16;

    char* ws = (char*)d_ws;
    size_t off = 0;
    auto alloc = [&](size_t bytes) -> char* {
        char* p = ws + off;
        off += (bytes + 255) & ~(size_t)255;
        return p;
    };
    float*        numP    = (float*)alloc((size_t)NS * 64 * 8192 * 4);  // 32 MB
    float*        denP    = (float*)alloc((size_t)NS * 8192 * 4);       // 512 KB
    unsigned long long* adjbits = (unsigned long long*)alloc(8192 * 1024); // 8 MB
    _Float16*     WhT0    = (_Float16*)alloc(64 * 8192 * 2);            // 1 MB
    _Float16*     WhT1    = (_Float16*)alloc(64 * 8192 * 2);            // 1 MB
    unsigned int* E12_0   = (unsigned int*)alloc(8192 * 4);
    unsigned int* E12_1   = (unsigned int*)alloc(8192 * 4);
    _Float16* F1h0 = (_Float16*)alloc(8192 * 2);
    _Float16* F2h0 = (_Float16*)alloc(8192 * 2);
    _Float16* F1h1 = (_Float16*)alloc(8192 * 2);
    _Float16* F2h1 = (_Float16*)alloc(8192 * 2);
    // ~43 MB total; every buffer fully overwritten each launch (0xAA-safe).

    const unsigned int* bits32 = (const unsigned int*)adjbits;

    // layer 0 (adj->bits fused into k_agg_l0: adj streamed once, overlapped)
    k_prep0<<<128, 256, 0, stream>>>(ue, ie, W0w, W0b, a0,
                                     WhT0, E12_0, F1h0, F2h0);
    k_agg_l0<<<dim3(64, NS), 256, 0, stream>>>(adj, adjbits, WhT0, E12_0,
                                               F1h0, F2h0, numP, denP);
    // layer 1
    k_prep1<NS><<<128, 256, 0, stream>>>(numP, denP, W1w, W1b, a1,
                                         WhT1, E12_1, F1h1, F2h1);
    k_agg_l1<<<dim3(64, NS), 256, 0, stream>>>(bits32, WhT1, E12_1,
                                               F1h1, F2h1, numP, denP);
    // output projection
    k_out<NS><<<128, 256, 0, stream>>>(numP, denP, Ow, Ob, (float*)d_out);
}